// Round 3
// baseline (153.103 us; speedup 1.0000x reference)
//
#include <hip/hip_runtime.h>

// apply_cdna_kernels: out[n,b,c,h,w] = sum_{kh,kw} images[b,h+kh-2,w+kw-2,c] * kernels[b,kh,kw,n]
// images: [64,128,128,3] f32   kernels: [64,5,5,10] f32   out: [10,64,3,128,128] f32
// Tile: 8 rows x 64 cols per block, 256 threads, 2 w-pixels per thread.

#define B_  64
#define H_  128
#define W_  128
#define C_  3
#define N_  10
#define KH_ 5
#define KW_ 5
#define TH_ 8
#define TWB 64                  // tile width in pixels (2 per thread)
#define HALO 2
#define LDS_ROW ((TWB + 2*HALO) * C_)           // 68*3 = 204 floats per row
#define LDS_ELEMS ((TH_ + 2*HALO) * LDS_ROW)    // 12*204 = 2448 floats (9.8 KB)

__global__ __launch_bounds__(256, 4) void cdna_apply_kernel(
    const float* __restrict__ images,
    const float* __restrict__ kernels,
    float* __restrict__ out)
{
    __shared__ float s_img[LDS_ELEMS];

    const int tid = threadIdx.x;
    const int bid = blockIdx.x;
    const int b   = bid >> 5;          // 32 tiles per batch image
    const int t   = bid & 31;
    const int by  = t >> 1;            // 16 tiles in H
    const int bx  = t & 1;             // 2 tiles in W
    const int y0  = by * TH_;
    const int x0  = bx * TWB;

    // ---- stage image tile into LDS ----
    // LDS row r maps LINEARLY to global float column x0*3 - 6 + r
    // (channel-interleaved layout matches global [h][w][c] exactly).
    const long img_base = (long)b * (H_ * W_ * C_);
    const int  colf0    = x0 * C_ - HALO * C_;     // may be negative at left edge
    #pragma unroll
    for (int k = 0; k < (LDS_ELEMS + 255) / 256; ++k) {
        int i = tid + k * 256;
        if (i < LDS_ELEMS) {
            int yy = i / LDS_ROW;                  // const divisor -> magic mul
            int r  = i - yy * LDS_ROW;
            int y  = y0 + yy - HALO;
            int cf = colf0 + r;                    // global float column
            float v = 0.0f;
            if ((unsigned)y < (unsigned)H_ && (unsigned)cf < (unsigned)(W_ * C_))
                v = images[img_base + (long)y * (W_ * C_) + cf];
            s_img[i] = v;
        }
    }
    __syncthreads();

    const int tx = tid & 31;           // 32 threads per row, 2 pixels each
    const int ty = tid >> 5;           // 8 rows

    const float* __restrict__ kb = kernels + b * (KH_ * KW_ * N_);

    float acc0[N_ * C_];               // pixel w = x0 + 2*tx
    float acc1[N_ * C_];               // pixel w = x0 + 2*tx + 1
    #pragma unroll
    for (int i = 0; i < N_ * C_; ++i) { acc0[i] = 0.0f; acc1[i] = 0.0f; }

    // Runtime kh loop keeps live set to 18 pixels + 50 weights + 60 accs.
    #pragma unroll 1
    for (int kh = 0; kh < KH_; ++kh) {
        // 18 contiguous floats cover both pixels' 5-tap windows (8B aligned).
        const float* row = &s_img[(ty + kh) * LDS_ROW + 6 * tx];
        float p[(KW_ + 1) * C_];       // 18
        #pragma unroll
        for (int i = 0; i < (KW_ + 1) * C_; ++i) p[i] = row[i];

        const float* __restrict__ wrow = kb + kh * (KW_ * N_);  // uniform -> s_load
        #pragma unroll
        for (int kw = 0; kw < KW_; ++kw) {
            #pragma unroll
            for (int n = 0; n < N_; ++n) {
                const float wgt = wrow[kw * N_ + n];
                #pragma unroll
                for (int c = 0; c < C_; ++c) {
                    acc0[n * C_ + c] = fmaf(p[kw * C_ + c],       wgt, acc0[n * C_ + c]);
                    acc1[n * C_ + c] = fmaf(p[kw * C_ + C_ + c],  wgt, acc1[n * C_ + c]);
                }
            }
        }
    }

    // ---- write out: out[n,b,c,h,w], float2 per thread, coalesced in w ----
    const int h = y0 + ty;
    const int w = x0 + 2 * tx;
    float* ob = out + (long)b * (C_ * H_ * W_) + (long)h * W_ + w;   // 8B aligned
    #pragma unroll
    for (int n = 0; n < N_; ++n) {
        #pragma unroll
        for (int c = 0; c < C_; ++c) {
            float2 v;
            v.x = acc0[n * C_ + c];
            v.y = acc1[n * C_ + c];
            *(float2*)(ob + (long)n * ((long)B_ * C_ * H_ * W_) + (long)c * (H_ * W_)) = v;
        }
    }
}

extern "C" void kernel_launch(void* const* d_in, const int* in_sizes, int n_in,
                              void* d_out, int out_size, void* d_ws, size_t ws_size,
                              hipStream_t stream) {
    const float* images  = (const float*)d_in[0];
    const float* kernels = (const float*)d_in[1];
    float* out = (float*)d_out;

    const int grid = B_ * (H_ / TH_) * (W_ / TWB);  // 64 * 16 * 2 = 2048
    cdna_apply_kernel<<<grid, 256, 0, stream>>>(images, kernels, out);
}